// Round 6
// baseline (4546.621 us; speedup 1.0000x reference)
//
#include <hip/hip_runtime.h>
#include <hip/hip_bf16.h>

// ---------------------------------------------------------------------------
// DEQ layer, MI355X round 5.
//  - Diagnosis: round-5 profile shows top dispatch = 55 us but wall = 1744 us
//    over ~120 serial small dispatches -> launch-gap bound.
//  - Fix: ONE persistent kernel (256 blocks x 256 thr, guaranteed co-resident:
//    24KB LDS => >=6 blocks/CU capacity) runs pmv chain + sigma + wfold +
//    warm-up + all 23 Anderson iterations, separated by software grid
//    barriers (monotonic ticket counter, agent-scope atomics + threadfence).
//  - gram pad 66 -> 65: staging-write bank = (c+r)&31 -> conflict-free.
//  - GEMM/Anderson arithmetic identical to verified rounds 2-5.
// ---------------------------------------------------------------------------

#define B_ROWS 2048
#define D_LAT  256
#define D_CTX  256
#define D_HID  1024
#define KCAT   512
#define SLOT   (B_ROWS * D_LAT)
#define NRING  7
#define NBLK   256u

typedef __bf16 bf16x8 __attribute__((ext_vector_type(8)));
typedef float f32x4 __attribute__((ext_vector_type(4)));
typedef unsigned short u16;

// ---------------- grid barrier (monotonic ticket) --------------------------
__device__ __forceinline__ void gbar(unsigned* cnt) {
  __syncthreads();
  if (threadIdx.x == 0) {
    __threadfence();  // agent-scope release (L2 writeback on gfx9xx)
    unsigned t = __hip_atomic_fetch_add(cnt, 1u, __ATOMIC_ACQ_REL,
                                        __HIP_MEMORY_SCOPE_AGENT);
    unsigned target = (t / NBLK + 1u) * NBLK;
    while (__hip_atomic_load(cnt, __ATOMIC_ACQUIRE,
                             __HIP_MEMORY_SCOPE_AGENT) < target)
      __builtin_amdgcn_s_sleep(2);
    __threadfence();  // agent-scope acquire (L1/L2 invalidate)
  }
  __syncthreads();
}

// ---------------- init: zc = [bf16(0)|bf16(ctx)], uA=1, vA=0, G=0 ----------
__global__ void init_kernel(const float* __restrict__ ctx,
                            __hip_bfloat16* __restrict__ zc,
                            float* __restrict__ vA, float* __restrict__ uA,
                            float* __restrict__ G1p, float* __restrict__ G2) {
  int i = blockIdx.x * 256 + threadIdx.x;
  if (i < B_ROWS * KCAT) {
    int b = i >> 9, c = i & 511;
    float v = (c < 256) ? 0.0f : ctx[b * 256 + (c - 256)];
    zc[i] = __float2bfloat16(v);
  }
  if (i < 512 * 512) G1p[i] = 0.0f;
  if (i < 256 * 256) G2[i] = 0.0f;
  if (i < KCAT) vA[i] = 0.0f;
  if (i < D_LAT) uA[i] = 1.0f;
}

// ---------------- Gram build, split-K x8, atomic accumulate ----------------
__global__ __launch_bounds__(256) void gram_kernel(
    const float* __restrict__ W1, const float* __restrict__ W2,
    float* __restrict__ G1p, float* __restrict__ G2) {
  __shared__ float As[32][65];   // pad 65: staging-write bank (c+r)&31, no conflict
  __shared__ float Bs[32][65];
  const int tid = threadIdx.x;
  const int tx = tid & 15, ty = tid >> 4;

  const float* X; float* G; int N, ti, tj, k0base; bool modeA;
  int b = blockIdx.x;
  if (b < 512) {
    modeA = true; X = W1; G = G1p; N = 512;
    int s = b >> 6, t = b & 63;
    ti = t >> 3; tj = t & 7; k0base = s * 128;
  } else {
    modeA = false; b -= 512; X = W2; G = G2; N = 256;
    int s = b >> 4, t = b & 15;
    ti = t >> 2; tj = t & 3; k0base = s * 128;
  }

  float acc[4][4] = {};
  for (int k0 = k0base; k0 < k0base + 128; k0 += 32) {
    if (modeA) {
      for (int idx = tid; idx < 2048; idx += 256) {
        int r = idx & 63, c = idx >> 6;
        As[c][r] = X[(size_t)(k0 + c) * 512 + ti * 64 + r];
        Bs[c][r] = X[(size_t)(k0 + c) * 512 + tj * 64 + r];
      }
    } else {
      for (int idx = tid; idx < 2048; idx += 256) {
        int c = idx & 31, r = idx >> 5;
        As[c][r] = X[(size_t)(ti * 64 + r) * 1024 + k0 + c];
        Bs[c][r] = X[(size_t)(tj * 64 + r) * 1024 + k0 + c];
      }
    }
    __syncthreads();
#pragma unroll
    for (int kk = 0; kk < 32; kk++) {
      float a[4], bb[4];
#pragma unroll
      for (int i = 0; i < 4; i++) a[i] = As[kk][ty * 4 + i];
#pragma unroll
      for (int j = 0; j < 4; j++) bb[j] = Bs[kk][tx * 4 + j];
#pragma unroll
      for (int i = 0; i < 4; i++)
#pragma unroll
        for (int j = 0; j < 4; j++) acc[i][j] += a[i] * bb[j];
    }
    __syncthreads();
  }
#pragma unroll
  for (int i = 0; i < 4; i++)
#pragma unroll
    for (int j = 0; j < 4; j++)
      atomicAdd(&G[(size_t)(ti * 64 + ty * 4 + i) * N + tj * 64 + tx * 4 + j],
                acc[i][j]);
}

// ---------------- colsum: vA += W1^T ones ----------------------------------
__global__ __launch_bounds__(256) void colsum_kernel(
    const float* __restrict__ W1, float* __restrict__ vA) {
  int b = blockIdx.x;
  for (int c = threadIdx.x; c < KCAT; c += 256) {
    float s = 0.f;
#pragma unroll
    for (int r = 0; r < 16; r++) s += W1[(size_t)(16 * b + r) * KCAT + c];
    atomicAdd(&vA[c], s);
  }
}

// ---------------- device fn: bf16 MFMA GEMM tile ---------------------------
// C = tanh(A @ W^T + bias) for one BM x BN tile at (bm, bn).
template <int BM, int BN, bool OUT_BF16>
__device__ __forceinline__ void gemm_tile(
    u16* lds, const __hip_bfloat16* A, const __hip_bfloat16* W, int K,
    const float* bias, float* Cf, __hip_bfloat16* Cb, int N, int bm, int bn) {
  u16* As = lds;
  u16* Ws = lds + BM * 64;
  const int tid = threadIdx.x;
  const int lane = tid & 63;
  const int wid = tid >> 6;
  const int wy = wid >> 1, wx = wid & 1;
  constexpr int WM = BM / 2, WN = BN / 2;
  constexpr int MB = WM / 16, NB = WN / 16;
  const int rlo = lane & 15, quad = lane >> 4;

  f32x4 acc[MB][NB] = {};

  for (int k0 = 0; k0 < K; k0 += 64) {
    for (int c = tid; c < BM * 8; c += 256) {
      int r = c >> 3, o = (c & 7) ^ (r & 7);
      __builtin_amdgcn_global_load_lds(
          (const __attribute__((address_space(1))) void*)(A + (size_t)(bm + r) * K + k0 + o * 8),
          (__attribute__((address_space(3))) void*)(As + c * 8), 16, 0, 0);
    }
    for (int c = tid; c < BN * 8; c += 256) {
      int r = c >> 3, o = (c & 7) ^ (r & 7);
      __builtin_amdgcn_global_load_lds(
          (const __attribute__((address_space(1))) void*)(W + (size_t)(bn + r) * K + k0 + o * 8),
          (__attribute__((address_space(3))) void*)(Ws + c * 8), 16, 0, 0);
    }
    __syncthreads();
#pragma unroll
    for (int kk = 0; kk < 2; kk++) {
      bf16x8 af[MB], bfr[NB];
#pragma unroll
      for (int mb = 0; mb < MB; mb++) {
        int r = wy * WM + mb * 16 + rlo;
        int o = (kk * 4 + quad) ^ (r & 7);
        af[mb] = *(const bf16x8*)(As + (r * 8 + o) * 8);
      }
#pragma unroll
      for (int nb = 0; nb < NB; nb++) {
        int r = wx * WN + nb * 16 + rlo;
        int o = (kk * 4 + quad) ^ (r & 7);
        bfr[nb] = *(const bf16x8*)(Ws + (r * 8 + o) * 8);
      }
#pragma unroll
      for (int mb = 0; mb < MB; mb++)
#pragma unroll
        for (int nb = 0; nb < NB; nb++)
          acc[mb][nb] = __builtin_amdgcn_mfma_f32_16x16x32_bf16(
              af[mb], bfr[nb], acc[mb][nb], 0, 0, 0);
    }
    __syncthreads();
  }

#pragma unroll
  for (int mb = 0; mb < MB; mb++) {
#pragma unroll
    for (int nb = 0; nb < NB; nb++) {
      int n = bn + wx * WN + nb * 16 + rlo;
      float bv = bias[n];
#pragma unroll
      for (int rg = 0; rg < 4; rg++) {
        int m = bm + wy * WM + mb * 16 + quad * 4 + rg;
        float val = tanhf(acc[mb][nb][rg] + bv);
        if constexpr (OUT_BF16) {
          Cb[(size_t)m * N + n] = __float2bfloat16(val);
        } else {
          Cf[(size_t)m * N + n] = val;
        }
      }
    }
  }
}

// ---------------- device fn: Anderson step for 8 rows of block b -----------
__device__ __forceinline__ void anderson_rows(
    const float* Xh, const float* Fh, float* Xw, __hip_bfloat16* zc, int t,
    int mk, int b) {
  const int lane = threadIdx.x & 63;
  const int w = threadIdx.x >> 6;
  for (int rr = 0; rr < 2; rr++) {
    const int row = b * 8 + w * 2 + rr;
    const int base = row * D_LAT + lane;

    float fa[4], xa[4], r[4], Fm1[4];
#pragma unroll
    for (int c = 0; c < 4; c++) {
      int sl = (t - 1) % NRING;
      fa[c] = Fh[sl * SLOT + base + 64 * c];
      xa[c] = Xh[sl * SLOT + base + 64 * c];
      r[c] = fa[c] - xa[c];
      Fm1[c] = fa[c];
    }

    float dF[5][4], dG[5][4];
    for (int i = 1; i <= mk; i++) {
      int sl = (t - 1 - i) % NRING;
#pragma unroll
      for (int c = 0; c < 4; c++) {
        float fb = Fh[sl * SLOT + base + 64 * c];
        float xb = Xh[sl * SLOT + base + 64 * c];
        dF[i - 1][c] = fa[c] - fb;
        float dx = xa[c] - xb;
        dG[i - 1][c] = dF[i - 1][c] - dx;
        fa[c] = fb;
        xa[c] = xb;
      }
    }

    float vals[20];
    int nv = 0;
    for (int i = 0; i < mk; i++)
      for (int j = i; j < mk; j++) {
        float s = 0.f;
#pragma unroll
        for (int c = 0; c < 4; c++) s += dG[i][c] * dG[j][c];
        vals[nv++] = s;
      }
    for (int i = 0; i < mk; i++) {
      float s = 0.f;
#pragma unroll
      for (int c = 0; c < 4; c++) s += dG[i][c] * r[c];
      vals[nv++] = s;
    }
    for (int off = 1; off <= 32; off <<= 1)
      for (int v = 0; v < nv; v++) vals[v] += __shfl_xor(vals[v], off, 64);

    double A[5][5], bv[5], alpha[5];
    int p = 0;
    for (int i = 0; i < mk; i++)
      for (int j = i; j < mk; j++) {
        A[i][j] = (double)vals[p];
        A[j][i] = (double)vals[p];
        p++;
      }
    for (int i = 0; i < mk; i++) A[i][i] += (double)1e-4f;
    for (int i = 0; i < mk; i++) bv[i] = (double)vals[p++];

    for (int c = 0; c < mk; c++) {
      double inv = 1.0 / A[c][c];
      for (int rw = c + 1; rw < mk; rw++) {
        double fct = A[rw][c] * inv;
        for (int cc = c; cc < mk; cc++) A[rw][cc] -= fct * A[c][cc];
        bv[rw] -= fct * bv[c];
      }
    }
    for (int i = mk - 1; i >= 0; i--) {
      double s = bv[i];
      for (int j = i + 1; j < mk; j++) s -= A[i][j] * alpha[j];
      alpha[i] = s / A[i][i];
    }

#pragma unroll
    for (int c = 0; c < 4; c++) {
      float x = Fm1[c];
      for (int i = 0; i < mk; i++) x -= dF[i][c] * (float)alpha[i];
      Xw[base + 64 * c] = x;
      if (zc != nullptr) zc[row * KCAT + lane + 64 * c] = __float2bfloat16(x);
    }
  }
}

// ---------------- THE persistent kernel ------------------------------------
__global__ __launch_bounds__(256) void deq_persistent(
    const float* W1, const float* W2, const float* b1, const float* b2,
    const float* G1p, const float* G2, float* vA, float* vB, float* uA,
    float* uB, float* sig, unsigned* cnt, float* Xh, float* Fh,
    __hip_bfloat16* W1b, __hip_bfloat16* W2b, __hip_bfloat16* zc,
    __hip_bfloat16* hb, float* out) {
  __shared__ __align__(16) u16 lds[(64 + 128) * 64];  // 24 KB
  __shared__ float red[4][4];
  const int b = blockIdx.x;
  const int tid = threadIdx.x;
  const int lane = tid & 63;
  const int w = tid >> 6;

  // phase 0: zero X history slot 0 (x0 = 0)
  for (int i = b * 256 + tid; i < SLOT; i += 65536) Xh[i] = 0.0f;

  // phase 1: damped Gram power chain (verified round-5 schedule)
  for (int it = 1; it <= 21; it++) {
    const float *vi, *ui;
    float *vo, *uo;
    if (it & 1) { vi = vB; vo = vA; ui = uA; uo = uB; }
    else        { vi = vA; vo = vB; ui = uB; uo = uA; }
    if (w == 2) {  // G2 row b
      const float4* Gr = (const float4*)(G2 + (size_t)b * 256);
      const float4* uv = (const float4*)ui;
      float4 g = Gr[lane], u = uv[lane];
      float acc = g.x * u.x + g.y * u.y + g.z * u.z + g.w * u.w;
      for (int off = 32; off; off >>= 1) acc += __shfl_down(acc, off, 64);
      if (lane == 0) uo[b] = 0.25f * acc;
    } else if (w < 2 && it >= 2) {  // G1' rows b, b+256
      int r = b + 256 * w;
      const float4* Gr = (const float4*)(G1p + (size_t)r * 512);
      const float4* uv = (const float4*)vi;
      float acc = 0.f;
#pragma unroll
      for (int c = 0; c < 2; c++) {
        float4 g = Gr[lane + 64 * c], u = uv[lane + 64 * c];
        acc += g.x * u.x + g.y * u.y + g.z * u.z + g.w * u.w;
      }
      for (int off = 32; off; off >>= 1) acc += __shfl_down(acc, off, 64);
      if (lane == 0) vo[r] = 0.25f * acc;
    }
    gbar(cnt);
  }

  // phase 2: sigma (block 0), then broadcast via global
  if (b == 0) {
    float s[4] = {0.f, 0.f, 0.f, 0.f};
    for (int i = tid; i < KCAT; i += 256) {
      s[0] += vA[i] * vB[i];
      s[1] += vA[i] * vA[i];
    }
    for (int i = tid; i < D_LAT; i += 256) {
      s[2] += uA[i] * uA[i];
      s[3] += uA[i] * uB[i];
    }
    for (int k = 0; k < 4; k++) {
      float a = s[k];
      for (int off = 32; off; off >>= 1) a += __shfl_down(a, off, 64);
      if (lane == 0) red[k][w] = a;
    }
    __syncthreads();
    if (tid == 0) {
      float d0 = red[0][0] + red[0][1] + red[0][2] + red[0][3];
      float d1 = red[1][0] + red[1][1] + red[1][2] + red[1][3];
      float d2 = red[2][0] + red[2][1] + red[2][2] + red[2][3];
      float d3 = red[3][0] + red[3][1] + red[3][2] + red[3][3];
      sig[0] = sqrtf(0.25f * d0 / d1);
      sig[1] = sqrtf(0.25f * d2 / d3);
    }
  }
  gbar(cnt);

  // phase 3: fold sigma into bf16 weights (grid-stride)
  {
    float s0 = sig[0], s1 = sig[1];
    for (int i = b * 256 + tid; i < D_HID * KCAT; i += 65536)
      W1b[i] = __float2bfloat16(W1[i] * s0);
    for (int i = b * 256 + tid; i < D_LAT * D_HID; i += 65536)
      W2b[i] = __float2bfloat16(W2[i] * s1);
  }
  gbar(cnt);

  const int bm1 = (b >> 3) * 64, bn1 = (b & 7) * 128;
  const int bm2 = (b >> 3) * 64, bn2 = (b & 7) * 32;

  // warm-up: F0 = f(x0)
  gemm_tile<64, 128, true>(lds, zc, W1b, KCAT, b1, nullptr, hb, D_HID, bm1, bn1);
  gbar(cnt);
  gemm_tile<64, 32, false>(lds, hb, W2b, D_HID, b2, Fh, nullptr, D_LAT, bm2, bn2);
  gbar(cnt);
  // X1 = F0; zc = bf16(F0)
  for (int i = b * 256 + tid; i < SLOT; i += 65536) {
    float v = Fh[i];
    Xh[SLOT + i] = v;
    zc[(i >> 8) * KCAT + (i & 255)] = __float2bfloat16(v);
  }
  gbar(cnt);
  // F1 = f(X1)
  gemm_tile<64, 128, true>(lds, zc, W1b, KCAT, b1, nullptr, hb, D_HID, bm1, bn1);
  gbar(cnt);
  gemm_tile<64, 32, false>(lds, hb, W2b, D_HID, b2, Fh + SLOT, nullptr, D_LAT, bm2, bn2);
  gbar(cnt);
  // X2 = F0; F2 = F1
  for (int i = b * 256 + tid; i < SLOT; i += 65536) {
    Xh[2 * SLOT + i] = Fh[i];
    Fh[2 * SLOT + i] = Fh[SLOT + i];
  }
  gbar(cnt);

  // Anderson loop: t = 3..25
  for (int t = 3; t <= 25; t++) {
    int mk = (t - 1 < 5) ? (t - 1) : 5;
    float* Xw = (t == 25) ? out : (Xh + (t % NRING) * SLOT);
    __hip_bfloat16* zarg = (t == 25) ? nullptr : zc;
    anderson_rows(Xh, Fh, Xw, zarg, t, mk, b);
    if (t == 25) break;
    gbar(cnt);
    gemm_tile<64, 128, true>(lds, zc, W1b, KCAT, b1, nullptr, hb, D_HID, bm1, bn1);
    gbar(cnt);
    gemm_tile<64, 32, false>(lds, hb, W2b, D_HID, b2, Fh + (t % NRING) * SLOT,
                             nullptr, D_LAT, bm2, bn2);
    gbar(cnt);
  }
}

// ---------------- host orchestration ---------------------------------------
extern "C" void kernel_launch(void* const* d_in, const int* in_sizes, int n_in,
                              void* d_out, int out_size, void* d_ws,
                              size_t ws_size, hipStream_t stream) {
  const float* ctx = (const float*)d_in[0];
  const float* W1 = (const float*)d_in[1];
  const float* b1 = (const float*)d_in[2];
  const float* W2 = (const float*)d_in[3];
  const float* b2 = (const float*)d_in[4];
  float* out = (float*)d_out;

  float* ws = (float*)d_ws;
  float* sig = ws;                        // [0..1]; cnt at ws+8
  unsigned* cnt = (unsigned*)(ws + 8);
  float* vA = ws + 16;                    // 512
  float* vB = vA + KCAT;                  // 512
  float* uA = vB + KCAT;                  // 256
  float* uB = uA + D_LAT;                 // 256
  float* G1p = uB + D_LAT;                // 512*512
  float* G2 = G1p + KCAT * KCAT;          // 256*256
  float* Xh = G2 + D_LAT * D_LAT;         // 7*SLOT
  float* Fh = Xh + NRING * SLOT;          // 7*SLOT
  __hip_bfloat16* W1b = (__hip_bfloat16*)(Fh + NRING * SLOT);  // 524288
  __hip_bfloat16* W2b = W1b + D_HID * KCAT;                    // 262144
  __hip_bfloat16* zc = W2b + D_LAT * D_HID;                    // 2048*512
  __hip_bfloat16* hb = zc + B_ROWS * KCAT;                     // 2048*1024

  // init: zc = [0|bf16(ctx)], uA = ones, vA = 0, G zeroed
  init_kernel<<<(B_ROWS * KCAT + 255) / 256, 256, 0, stream>>>(ctx, zc, vA, uA,
                                                               G1p, G2);
  // Gram matrices + v1 = W1^T ones
  gram_kernel<<<640, 256, 0, stream>>>(W1, W2, G1p, G2);
  colsum_kernel<<<64, 256, 0, stream>>>(W1, vA);
  // barrier counter must start at 0 (ws is poisoned 0xAA each call)
  hipMemsetAsync(cnt, 0, sizeof(unsigned), stream);

  // everything else in one persistent kernel
  deq_persistent<<<NBLK, 256, 0, stream>>>(W1, W2, b1, b2, G1p, G2, vA, vB, uA,
                                           uB, sig, cnt, Xh, Fh, W1b, W2b, zc,
                                           hb, out);
}